// Round 6
// baseline (3219.181 us; speedup 1.0000x reference)
//
#include <hip/hip_runtime.h>
#include <cstdint>

typedef _Float16 f16;
typedef _Float16 f16x2 __attribute__((ext_vector_type(2)));

#define T_STEPS 512
#define B_SZ 512
#define LOG2PI 1.8378770664093453f

__device__ __forceinline__ void barrier_lds() {
  asm volatile("s_waitcnt lgkmcnt(0)" ::: "memory");
  __builtin_amdgcn_s_barrier();
  asm volatile("" ::: "memory");
}

__device__ __forceinline__ uint32_t packh2(float a, float b) {
  f16x2 v; v[0] = (f16)a; v[1] = (f16)b;
  return __builtin_bit_cast(uint32_t, v);
}

__device__ __forceinline__ float fdot2(uint32_t a, uint32_t b, float c) {
#if defined(__AMDGCN__) && __has_builtin(__builtin_amdgcn_fdot2)
  return __builtin_amdgcn_fdot2(__builtin_bit_cast(f16x2, a),
                                __builtin_bit_cast(f16x2, b), c, false);
#else
  f16x2 x = __builtin_bit_cast(f16x2, a), y = __builtin_bit_cast(f16x2, b);
  return c + (float)x[0] * (float)y[0] + (float)x[1] * (float)y[1];
#endif
}

#define DOT4(acc, w0, w1, w2, w3, v)                                     \
  do {                                                                   \
    acc = fdot2((w0), (v).x, acc); acc = fdot2((w1), (v).y, acc);        \
    acc = fdot2((w2), (v).z, acc); acc = fdot2((w3), (v).w, acc);        \
  } while (0)

__device__ __forceinline__ float sigmoidf_(float x) {
  return 1.0f / (1.0f + __expf(-x));
}
__device__ __forceinline__ float tanhf_(float x) {
  float ax = fabsf(x);
  float t = __expf(-2.0f * ax);
  float r = (1.0f - t) / (1.0f + t);
  return copysignf(r, x);
}
__device__ __forceinline__ float softplusf_(float x) {
  return fmaxf(x, 0.0f) + __logf(1.0f + __expf(-fabsf(x)));
}
__device__ __forceinline__ float asf_(uint32_t u) {
  return __builtin_bit_cast(float, u);
}

// ---------------------------------------------------------------------------
// Kernel 1: embedding / state_t construction.  state_t: (T,B,32) f16.
// ---------------------------------------------------------------------------
__global__ __launch_bounds__(256) void k_embed(
    const float* __restrict__ xs, const float* __restrict__ shot_emb,
    const float* __restrict__ player_emb, f16* __restrict__ state_t,
    float* __restrict__ accums) {
  if (blockIdx.x == 0 && threadIdx.x < 16) accums[threadIdx.x] = 0.0f;
  size_t idx = (size_t)blockIdx.x * 256 + threadIdx.x;
  const float* xp = xs + idx * 23;
  f16* op = state_t + idx * 32;
  int sid = (int)xp[12];
  int pid = (int)xp[17];
#pragma unroll
  for (int i = 0; i < 12; ++i) op[i] = (f16)xp[i];
  const float* se = shot_emb + sid * 8;
#pragma unroll
  for (int i = 0; i < 8; ++i) op[12 + i] = (f16)se[i];
#pragma unroll
  for (int i = 0; i < 4; ++i) op[20 + i] = (f16)xp[13 + i];
  const float* pe = player_emb + pid * 8;
#pragma unroll
  for (int i = 0; i < 8; ++i) op[24 + i] = (f16)pe[i];
}

// ---------------------------------------------------------------------------
// Kernel 2: backward GRU scan + encoder + qz0 head.  (R4-verified version)
// 256 blocks x 512 threads, 2 batch/block. Weights REGISTER-resident.
// ---------------------------------------------------------------------------
__global__ __launch_bounds__(512) void k_gru(
    const f16* __restrict__ state_t, const float* __restrict__ wih,
    const float* __restrict__ whh, const float* __restrict__ bih,
    const float* __restrict__ bhh, const float* __restrict__ enc_w,
    const float* __restrict__ enc_b, const float* __restrict__ qz0_w,
    const float* __restrict__ qz0_b, const float* __restrict__ z0_noise,
    const float* __restrict__ pz0_mean, const float* __restrict__ pz0_logstd,
    f16* __restrict__ ctx, float* __restrict__ z0_out,
    float* __restrict__ accums) {
  __shared__ uint32_t s_x[2][16];      // x_t, f16x2 packed
  __shared__ uint32_t s_h[2][64];      // h,   f16x2 packed
  __shared__ float s_gates[2 * 128 * 4];  // [b][du][R,Z,iN,hN]
  __shared__ float s_encp[2 * 64 * 2];    // [b][c][ks]
  __shared__ float s_ctx0[2][64];
  __shared__ float s_q[2][32];

  const int tid = threadIdx.x;
  const int bbase = blockIdx.x * 2;
  const uint32_t* stu = (const uint32_t*)state_t;

  uint32_t wA[64];   // whh row (RZ/N) | enc half-row (enc, 32 used)
  uint32_t wB[16];   // wih row (RZ/N)
  float bias0 = 0.f, bias1 = 0.f, encbr = 0.f;

  if (tid < 256) {
    int g = tid >> 7, du = tid & 127;
    const float* whr = whh + (size_t)(g * 128 + du) * 128;
#pragma unroll
    for (int i = 0; i < 64; ++i) wA[i] = packh2(whr[2 * i], whr[2 * i + 1]);
    const float* wxr = wih + (size_t)(g * 128 + du) * 32;
#pragma unroll
    for (int i = 0; i < 16; ++i) wB[i] = packh2(wxr[2 * i], wxr[2 * i + 1]);
    bias0 = bih[g * 128 + du] + bhh[g * 128 + du];
  } else if (tid < 384) {
    int du = tid - 256;
    const float* whr = whh + (size_t)(256 + du) * 128;
#pragma unroll
    for (int i = 0; i < 64; ++i) wA[i] = packh2(whr[2 * i], whr[2 * i + 1]);
    const float* wxr = wih + (size_t)(256 + du) * 32;
#pragma unroll
    for (int i = 0; i < 16; ++i) wB[i] = packh2(wxr[2 * i], wxr[2 * i + 1]);
    bias0 = bih[256 + du];
    bias1 = bhh[256 + du];
  } else {
    int e = tid - 384, c = e & 63, ks = e >> 6;
    const float* wer = enc_w + (size_t)c * 128 + ks * 64;
#pragma unroll
    for (int i = 0; i < 32; ++i) wA[i] = packh2(wer[2 * i], wer[2 * i + 1]);
    encbr = enc_b[c];
  }

  if (tid < 128) s_h[tid >> 6][tid & 63] = 0u;
  if (tid < 32) {
    int b = tid >> 4, i = tid & 15;
    s_x[b][i] = stu[((size_t)(T_STEPS - 1) * B_SZ + bbase + b) * 16 + i];
  }
  float h_old = 0.0f;
  __syncthreads();

  for (int t = T_STEPS - 1; t >= 0; --t) {
    uint4 xpref = make_uint4(0, 0, 0, 0);
    // ---- Phase A: gate dots (R/Z/N) + enc dots for h(t+1) + x prefetch
    if (tid < 256) {
      int g = tid >> 7, du = tid & 127;
#pragma unroll
      for (int b = 0; b < 2; ++b) {
        float a = bias0;
        const uint4* xq = (const uint4*)&s_x[b][0];
#pragma unroll
        for (int j = 0; j < 4; ++j) {
          uint4 v = xq[j];
          DOT4(a, wB[4 * j], wB[4 * j + 1], wB[4 * j + 2], wB[4 * j + 3], v);
        }
        const uint4* hq = (const uint4*)&s_h[b][0];
#pragma unroll
        for (int j = 0; j < 16; ++j) {
          uint4 v = hq[j];
          DOT4(a, wA[4 * j], wA[4 * j + 1], wA[4 * j + 2], wA[4 * j + 3], v);
        }
        s_gates[(b * 128 + du) * 4 + g] = a;
      }
    } else if (tid < 384) {
      int du = tid - 256;
#pragma unroll
      for (int b = 0; b < 2; ++b) {
        float aI = bias0, aH = bias1;
        const uint4* xq = (const uint4*)&s_x[b][0];
#pragma unroll
        for (int j = 0; j < 4; ++j) {
          uint4 v = xq[j];
          DOT4(aI, wB[4 * j], wB[4 * j + 1], wB[4 * j + 2], wB[4 * j + 3], v);
        }
        const uint4* hq = (const uint4*)&s_h[b][0];
#pragma unroll
        for (int j = 0; j < 16; ++j) {
          uint4 v = hq[j];
          DOT4(aH, wA[4 * j], wA[4 * j + 1], wA[4 * j + 2], wA[4 * j + 3], v);
        }
        s_gates[(b * 128 + du) * 4 + 2] = aI;
        s_gates[(b * 128 + du) * 4 + 3] = aH;
      }
    } else {
      int e = tid - 384, ks = e >> 6, cc = e & 63;
      (void)cc;
      if (t < T_STEPS - 1) {
#pragma unroll
        for (int b = 0; b < 2; ++b) {
          float a = 0.f;
          const uint4* hq = (const uint4*)&s_h[b][ks * 32];
#pragma unroll
          for (int j = 0; j < 8; ++j) {
            uint4 v = hq[j];
            DOT4(a, wA[4 * j], wA[4 * j + 1], wA[4 * j + 2], wA[4 * j + 3], v);
          }
          s_encp[(b * 64 + cc) * 2 + ks] = a;
        }
      }
      if (e < 8 && t > 0) {
        int b = e & 1, q = e >> 1;
        xpref = *(const uint4*)(stu +
                                ((size_t)(t - 1) * B_SZ + bbase + b) * 16 + q * 4);
      }
    }
    barrier_lds();
    // ---- Phase B: h update; ctx combine; x stage
    if (tid < 256) {
      int b = tid >> 7, du = tid & 127;
      const float4 gt = *(const float4*)&s_gates[(b * 128 + du) * 4];
      float r = sigmoidf_(gt.x), zg = sigmoidf_(gt.y);
      float n = tanhf_(gt.z + r * gt.w);
      float hnew = (1.0f - zg) * n + zg * h_old;
      h_old = hnew;
      ((f16*)&s_h[b][0])[du] = (f16)hnew;
    } else if (tid >= 384) {
      int e = tid - 384, cc = e & 63, b = e >> 6;
      if (t < T_STEPS - 1) {
        float2 p = *(const float2*)&s_encp[(b * 64 + cc) * 2];
        ctx[((size_t)(t + 1) * B_SZ + bbase + b) * 64 + cc] =
            (f16)(p.x + p.y + encbr);
      }
      if (e < 8 && t > 0) {
        int b2 = e & 1, q = e >> 1;
        *(uint4*)&s_x[b2][q * 4] = xpref;
      }
    }
    barrier_lds();
  }

  // ---- Tail: enc(h(0)) -> ctx[0] + s_ctx0; qz0 head; z0 + KL
  if (tid >= 384) {
    int e = tid - 384, ks = e >> 6, cc = e & 63;
#pragma unroll
    for (int b = 0; b < 2; ++b) {
      float a = 0.f;
      const uint4* hq = (const uint4*)&s_h[b][ks * 32];
#pragma unroll
      for (int j = 0; j < 8; ++j) {
        uint4 v = hq[j];
        DOT4(a, wA[4 * j], wA[4 * j + 1], wA[4 * j + 2], wA[4 * j + 3], v);
      }
      s_encp[(b * 64 + cc) * 2 + ks] = a;
    }
  }
  __syncthreads();
  if (tid >= 384) {
    int e = tid - 384, cc = e & 63, b = e >> 6;
    float2 p = *(const float2*)&s_encp[(b * 64 + cc) * 2];
    float val = p.x + p.y + encbr;
    ctx[((size_t)bbase + b) * 64 + cc] = (f16)val;
    s_ctx0[b][cc] = val;
  }
  __syncthreads();
  if (tid < 64) {
    int b = tid >> 5, o = tid & 31;
    float acc = qz0_b[o];
#pragma unroll 8
    for (int k = 0; k < 64; ++k) acc += qz0_w[o * 64 + k] * s_ctx0[b][k];
    s_q[b][o] = acc;
  }
  __syncthreads();
  if (tid < 32) {
    int b = tid >> 4, l = tid & 15;
    int bg = bbase + b;
    float qm = s_q[b][l], qls = s_q[b][16 + l];
    float z0v = qm + __expf(qls) * z0_noise[bg * 16 + l];
    z0_out[bg * 16 + l] = z0v;
    float pm = pz0_mean[l], pls = pz0_logstd[l];
    float var_q = __expf(2.0f * qls);
    float var_p = __expf(2.0f * pls);
    float dm = qm - pm;
    float kl = pls - qls + (var_q + dm * dm) / (2.0f * var_p) - 0.5f;
    atomicAdd(&accums[5], kl);
  }
}

// ---------------------------------------------------------------------------
// Kernel 3: SDE scan, ONE WAVE PER BATCH.  512 blocks x 64 threads.
// NO barriers in the loop: intra-wave LDS produce->consume is ordered by the
// compiler's lgkmcnt waits (lockstep lanes).  This deletes the ~4000-cycle
// per-step barrier/phase skeleton measured across R0-R4.
// Per lane: rows (2ln, 2ln+1) of the 128-wide layers; f2/h2 weights in
// REGISTERS (256 VGPR); f1/h1/f3/h3/g weights in per-lane LDS blobs with
// odd uint4 strides (bank-spread).  kc = ln&3 slices K for f3/h3/g; shfl_xor
// 1,2 reduces deliver results to the (ln&3)==0 lanes which own z[l=ln>>2].
// ---------------------------------------------------------------------------
__global__ __launch_bounds__(64, 1) void k_sde(
    const f16* __restrict__ ctx, const float* __restrict__ z0_in,
    const float* __restrict__ ts, const float* __restrict__ bm_noise,
    const float* __restrict__ fw1, const float* __restrict__ fb1,
    const float* __restrict__ fw2, const float* __restrict__ fb2,
    const float* __restrict__ fw3, const float* __restrict__ fb3,
    const float* __restrict__ hw1, const float* __restrict__ hb1,
    const float* __restrict__ hw2, const float* __restrict__ hb2,
    const float* __restrict__ hw3, const float* __restrict__ hb3,
    const float* __restrict__ gw1, const float* __restrict__ gb1,
    const float* __restrict__ gw2, const float* __restrict__ gb2,
    f16* __restrict__ zs, float* __restrict__ accums) {
  __shared__ uint4 f1w[64][21];  // [ln]: rows 2ln (u4 0..9), 2ln+1 (10..19) of fw1, f16
  __shared__ uint4 h1w[64][5];   // [ln]: rows 2ln (0..1), 2ln+1 (2..3) of hw1, f16
  __shared__ uint4 f3w[64][5];   // [ln]: fw3 row o=ln>>2, k-slice kc*32..+32 (0..3)
  __shared__ uint4 h3w[64][5];
  __shared__ uint4 gB[64][25];   // [ln]: f32 w1[0..7], b1[8..15], w2[16..23] for 32 h-slots
  __shared__ uint4 x2s[10];      // [z 16 f16 | ctx 64 f16]
  __shared__ uint4 h1f[16], h1h[16], h2f[16], h2h[16];  // activations, f16[128]
  __shared__ float s_zf[16];
  __shared__ float s_dts[T_STEPS];

  const int ln = threadIdx.x;
  const int bg = blockIdx.x;
  const int l = ln >> 2, kc = ln & 3;
  const int r0 = 2 * ln, r1 = 2 * ln + 1;

  // ---- weight init: per-lane LDS blobs
  {
    uint32_t* p = (uint32_t*)&f1w[ln][0];
    const float* wa = fw1 + (size_t)r0 * 80;
    const float* wb = fw1 + (size_t)r1 * 80;
#pragma unroll
    for (int i = 0; i < 40; ++i) {
      p[i] = packh2(wa[2 * i], wa[2 * i + 1]);
      p[40 + i] = packh2(wb[2 * i], wb[2 * i + 1]);
    }
  }
  {
    uint32_t* p = (uint32_t*)&h1w[ln][0];
    const float* wa = hw1 + (size_t)r0 * 16;
    const float* wb = hw1 + (size_t)r1 * 16;
#pragma unroll
    for (int i = 0; i < 8; ++i) {
      p[i] = packh2(wa[2 * i], wa[2 * i + 1]);
      p[8 + i] = packh2(wb[2 * i], wb[2 * i + 1]);
    }
  }
  {
    uint32_t* p = (uint32_t*)&f3w[ln][0];
    uint32_t* q = (uint32_t*)&h3w[ln][0];
    const float* wa = fw3 + (size_t)l * 128 + kc * 32;
    const float* wb = hw3 + (size_t)l * 128 + kc * 32;
#pragma unroll
    for (int i = 0; i < 16; ++i) {
      p[i] = packh2(wa[2 * i], wa[2 * i + 1]);
      q[i] = packh2(wb[2 * i], wb[2 * i + 1]);
    }
  }
  {
    float* gp = (float*)&gB[ln][0];
    const int hb = kc * 32;
#pragma unroll
    for (int j = 0; j < 32; ++j) {
      gp[j] = gw1[l * 128 + hb + j];
      gp[32 + j] = gb1[l * 128 + hb + j];
      gp[64 + j] = gw2[l * 128 + hb + j];
    }
  }
  // ---- f2/h2 weights into registers (2 rows each)
  uint4 f2a[16], f2b[16], h2a[16], h2b[16];
  {
    const float* wa = fw2 + (size_t)r0 * 128;
    const float* wb = fw2 + (size_t)r1 * 128;
    const float* wc = hw2 + (size_t)r0 * 128;
    const float* wd = hw2 + (size_t)r1 * 128;
#pragma unroll
    for (int j = 0; j < 16; ++j) {
      uint4 u;
      u.x = packh2(wa[8 * j + 0], wa[8 * j + 1]);
      u.y = packh2(wa[8 * j + 2], wa[8 * j + 3]);
      u.z = packh2(wa[8 * j + 4], wa[8 * j + 5]);
      u.w = packh2(wa[8 * j + 6], wa[8 * j + 7]);
      f2a[j] = u;
      u.x = packh2(wb[8 * j + 0], wb[8 * j + 1]);
      u.y = packh2(wb[8 * j + 2], wb[8 * j + 3]);
      u.z = packh2(wb[8 * j + 4], wb[8 * j + 5]);
      u.w = packh2(wb[8 * j + 6], wb[8 * j + 7]);
      f2b[j] = u;
      u.x = packh2(wc[8 * j + 0], wc[8 * j + 1]);
      u.y = packh2(wc[8 * j + 2], wc[8 * j + 3]);
      u.z = packh2(wc[8 * j + 4], wc[8 * j + 5]);
      u.w = packh2(wc[8 * j + 6], wc[8 * j + 7]);
      h2a[j] = u;
      u.x = packh2(wd[8 * j + 0], wd[8 * j + 1]);
      u.y = packh2(wd[8 * j + 2], wd[8 * j + 3]);
      u.z = packh2(wd[8 * j + 4], wd[8 * j + 5]);
      u.w = packh2(wd[8 * j + 6], wd[8 * j + 7]);
      h2b[j] = u;
    }
  }
  const float bf1a = fb1[r0], bf1b = fb1[r1];
  const float bh1a = hb1[r0], bh1b = hb1[r1];
  const float bf2a = fb2[r0], bf2b = fb2[r1];
  const float bh2a = hb2[r0], bh2b = hb2[r1];
  const float fb3r = fb3[l], hb3r = hb3[l], gb2r = gb2[l];

  for (int i = ln; i < T_STEPS - 1; i += 64) s_dts[i] = ts[i + 1] - ts[i];

  const uint4* ctx4 = (const uint4*)ctx;
  uint4 cpref = make_uint4(0, 0, 0, 0);
  float bmc = 0.f, bmn = 0.f, path_acc = 0.f;
  if (kc == 0) {
    float z = z0_in[bg * 16 + l];
    s_zf[l] = z;
    ((f16*)&x2s[0])[l] = (f16)z;
    zs[(size_t)bg * 16 + l] = (f16)z;
    bmc = bm_noise[(size_t)bg * 16 + l];
  }
  if (ln < 8) cpref = ctx4[((size_t)1 * B_SZ + bg) * 8 + ln];
  __syncthreads();

  for (int t = 0; t < T_STEPS - 1; ++t) {
    // ---- stage ctx(t+1) into x2; issue prefetches for next iter
    if (ln < 8) x2s[2 + ln] = cpref;
    if (kc == 0 && t < T_STEPS - 2)
      bmn = bm_noise[((size_t)(t + 1) * B_SZ + bg) * 16 + l];
    if (ln < 8 && t <= T_STEPS - 3)
      cpref = ctx4[((size_t)(t + 2) * B_SZ + bg) * 8 + ln];
    asm volatile("" ::: "memory");

    // ---- g-net (reads s_zf from prev iter; independent stream)
    float y = s_zf[l];
    float gacc = 0.f;
#pragma unroll
    for (int q = 0; q < 8; ++q) {
      uint4 w1q = gB[ln][q], b1q = gB[ln][8 + q], w2q = gB[ln][16 + q];
      gacc = fmaf(softplusf_(fmaf(y, asf_(w1q.x), asf_(b1q.x))), asf_(w2q.x), gacc);
      gacc = fmaf(softplusf_(fmaf(y, asf_(w1q.y), asf_(b1q.y))), asf_(w2q.y), gacc);
      gacc = fmaf(softplusf_(fmaf(y, asf_(w1q.z), asf_(b1q.z))), asf_(w2q.z), gacc);
      gacc = fmaf(softplusf_(fmaf(y, asf_(w1q.w), asf_(b1q.w))), asf_(w2q.w), gacc);
    }
    gacc += __shfl_xor(gacc, 1);
    gacc += __shfl_xor(gacc, 2);

    // ---- layer 1: f1 (80-wide) + h1 (16-wide), 2 rows each
    float a00 = bf1a, a01 = 0.f, a10 = bf1b, a11 = 0.f;
#pragma unroll
    for (int j = 0; j < 10; ++j) {
      uint4 xv = x2s[j];
      uint4 w0 = f1w[ln][j];
      uint4 w1v = f1w[ln][10 + j];
      if (j & 1) {
        DOT4(a01, w0.x, w0.y, w0.z, w0.w, xv);
        DOT4(a11, w1v.x, w1v.y, w1v.z, w1v.w, xv);
      } else {
        DOT4(a00, w0.x, w0.y, w0.z, w0.w, xv);
        DOT4(a10, w1v.x, w1v.y, w1v.z, w1v.w, xv);
      }
    }
    ((uint32_t*)h1f)[ln] = packh2(softplusf_(a00 + a01), softplusf_(a10 + a11));
    float c0 = bh1a, c1 = bh1b;
    {
      uint4 xv = x2s[0];
      uint4 wz0 = h1w[ln][0], wz2 = h1w[ln][2];
      DOT4(c0, wz0.x, wz0.y, wz0.z, wz0.w, xv);
      DOT4(c1, wz2.x, wz2.y, wz2.z, wz2.w, xv);
      xv = x2s[1];
      uint4 wz1 = h1w[ln][1], wz3 = h1w[ln][3];
      DOT4(c0, wz1.x, wz1.y, wz1.z, wz1.w, xv);
      DOT4(c1, wz3.x, wz3.y, wz3.z, wz3.w, xv);
    }
    ((uint32_t*)h1h)[ln] = packh2(softplusf_(c0), softplusf_(c1));
    asm volatile("" ::: "memory");

    // ---- layer 2: f2 + h2 (128-wide), weights in registers
    float d00 = bf2a, d01 = 0.f, d10 = bf2b, d11 = 0.f;
    float e00 = bh2a, e01 = 0.f, e10 = bh2b, e11 = 0.f;
#pragma unroll
    for (int j = 0; j < 16; ++j) {
      uint4 vf = h1f[j];
      uint4 vh = h1h[j];
      if (j & 1) {
        DOT4(d01, f2a[j].x, f2a[j].y, f2a[j].z, f2a[j].w, vf);
        DOT4(d11, f2b[j].x, f2b[j].y, f2b[j].z, f2b[j].w, vf);
        DOT4(e01, h2a[j].x, h2a[j].y, h2a[j].z, h2a[j].w, vh);
        DOT4(e11, h2b[j].x, h2b[j].y, h2b[j].z, h2b[j].w, vh);
      } else {
        DOT4(d00, f2a[j].x, f2a[j].y, f2a[j].z, f2a[j].w, vf);
        DOT4(d10, f2b[j].x, f2b[j].y, f2b[j].z, f2b[j].w, vf);
        DOT4(e00, h2a[j].x, h2a[j].y, h2a[j].z, h2a[j].w, vh);
        DOT4(e10, h2b[j].x, h2b[j].y, h2b[j].z, h2b[j].w, vh);
      }
    }
    ((uint32_t*)h2f)[ln] = packh2(softplusf_(d00 + d01), softplusf_(d10 + d11));
    ((uint32_t*)h2h)[ln] = packh2(softplusf_(e00 + e01), softplusf_(e10 + e11));
    asm volatile("" ::: "memory");

    // ---- layer 3: f3 + h3 partials over k-slice kc*32..+32, 4-lane reduce
    float p3 = 0.f, q3 = 0.f;
#pragma unroll
    for (int j = 0; j < 4; ++j) {
      uint4 vf = h2f[kc * 4 + j];
      uint4 wf = f3w[ln][j];
      DOT4(p3, wf.x, wf.y, wf.z, wf.w, vf);
      uint4 vh = h2h[kc * 4 + j];
      uint4 wh = h3w[ln][j];
      DOT4(q3, wh.x, wh.y, wh.z, wh.w, vh);
    }
    p3 += __shfl_xor(p3, 1);
    p3 += __shfl_xor(p3, 2);
    q3 += __shfl_xor(q3, 1);
    q3 += __shfl_xor(q3, 2);

    // ---- z update on (ln&3)==0 lanes
    if (kc == 0) {
      float fv = p3 + fb3r;
      float hv = q3 + hb3r;
      float gv = sigmoidf_(gacc + gb2r);
      float dt = s_dts[t];
      float u_ = (fv - hv) / gv;
      float lsum = u_ * u_;
      lsum += __shfl_xor(lsum, 4);
      lsum += __shfl_xor(lsum, 8);
      lsum += __shfl_xor(lsum, 16);
      lsum += __shfl_xor(lsum, 32);
      if (ln == 0) path_acc += 0.5f * lsum * dt;
      float dw = sqrtf(dt) * bmc;
      float zn = s_zf[l] + fv * dt + gv * dw;
      s_zf[l] = zn;
      ((f16*)&x2s[0])[l] = (f16)zn;
      zs[((size_t)(t + 1) * B_SZ + bg) * 16 + l] = (f16)zn;
      bmc = bmn;
    }
    asm volatile("" ::: "memory");
  }
  if (ln == 0) atomicAdd(&accums[6], path_acc);
}

// ---------------------------------------------------------------------------
// Kernel 4: decoder + losses.  One thread per (t,b).
// ---------------------------------------------------------------------------
__global__ __launch_bounds__(256) void k_dec(
    const f16* __restrict__ zs, const f16* __restrict__ state_t,
    const float* __restrict__ xs, const float* __restrict__ proj_w,
    const float* __restrict__ proj_b, const float* __restrict__ act_w,
    const float* __restrict__ act_b, const float* __restrict__ land_w,
    const float* __restrict__ shot_w, const float* __restrict__ move_w,
    float* __restrict__ accums) {
  __shared__ uint32_t s_proj[8 * 32];
  __shared__ uint32_t s_act[8 * 128];
  __shared__ uint32_t s_head[128 * 8];
  __shared__ float s_pb[32], s_ab[128];
  __shared__ float s_red[4 * 5];

  const int tid = threadIdx.x;
  for (int id = tid; id < 8 * 32; id += 256) {
    int kp = id & 7, n = id >> 3;
    s_proj[kp * 32 + n] = packh2(proj_w[n * 16 + 2 * kp], proj_w[n * 16 + 2 * kp + 1]);
  }
  for (int id = tid; id < 8 * 128; id += 256) {
    int kp = id & 7, n = id >> 3;
    s_act[kp * 128 + n] = packh2(act_w[n * 16 + 2 * kp], act_w[n * 16 + 2 * kp + 1]);
  }
  for (int id = tid; id < 128 * 8; id += 256) {
    int j = id >> 3, p = id & 7;
    int h0 = 2 * p, h1 = 2 * p + 1;
    float w0 = (h0 < 2) ? land_w[h0 * 128 + j]
                        : (h0 < 14 ? shot_w[(h0 - 2) * 128 + j]
                                   : move_w[(h0 - 14) * 128 + j]);
    float w1 = (h1 < 2) ? land_w[h1 * 128 + j]
                        : (h1 < 14 ? shot_w[(h1 - 2) * 128 + j]
                                   : move_w[(h1 - 14) * 128 + j]);
    s_head[j * 8 + p] = packh2(w0, w1);
  }
  if (tid < 32) s_pb[tid] = proj_b[tid];
  if (tid < 128) s_ab[tid] = act_b[tid];
  __syncthreads();

  size_t idx = (size_t)blockIdx.x * 256 + tid;
  uint32_t z2[8];
  const uint32_t* zp = (const uint32_t*)(zs + idx * 16);
#pragma unroll
  for (int i = 0; i < 8; ++i) z2[i] = zp[i];
  uint32_t stv[16];
  const uint32_t* stp = (const uint32_t*)(state_t + idx * 32);
#pragma unroll
  for (int i = 0; i < 16; ++i) stv[i] = stp[i];

  float sqsum = 0.0f;
#pragma unroll 4
  for (int i = 0; i < 32; ++i) {
    float acc = s_pb[i];
#pragma unroll
    for (int kp = 0; kp < 8; ++kp) acc = fdot2(s_proj[kp * 32 + i], z2[kp], acc);
    f16x2 sv = __builtin_bit_cast(f16x2, stv[i >> 1]);
    float d = (float)sv[i & 1] - acc;
    sqsum += d * d;
  }

  float hd[16];
#pragma unroll
  for (int i = 0; i < 16; ++i) hd[i] = 0.0f;
#pragma unroll 2
  for (int j = 0; j < 128; ++j) {
    float a = s_ab[j];
#pragma unroll
    for (int kp = 0; kp < 8; ++kp) a = fdot2(s_act[kp * 128 + j], z2[kp], a);
    a = fmaxf(a, 0.0f);
#pragma unroll
    for (int p = 0; p < 8; ++p) {
      f16x2 w = __builtin_bit_cast(f16x2, s_head[j * 8 + p]);
      hd[2 * p] += (float)w[0] * a;
      hd[2 * p + 1] += (float)w[1] * a;
    }
  }
  const float* xp = xs + idx * 23;
  float dl0 = hd[0] - xp[18], dl1 = hd[1] - xp[19];
  float land = dl0 * dl0 + dl1 * dl1;
  float dm0 = hd[14] - xp[21], dm1 = hd[15] - xp[22];
  float move = dm0 * dm0 + dm1 * dm1;
  int sid = (int)xp[20];
  float m = hd[2];
#pragma unroll
  for (int s = 1; s < 12; ++s) m = fmaxf(m, hd[2 + s]);
  float sume = 0.0f;
#pragma unroll
  for (int s = 0; s < 12; ++s) sume += __expf(hd[2 + s] - m);
  float lse = m + __logf(sume);
  float pl = 0.0f;
#pragma unroll
  for (int s = 0; s < 12; ++s)
    if (s == sid) pl = hd[2 + s];
  float picked = 0.0f, cnt = 0.0f;
  if (sid != 0) {
    picked = pl - lse;
    cnt = 1.0f;
  }
  float vals[5] = {sqsum, land, move, picked, cnt};
#pragma unroll
  for (int v = 0; v < 5; ++v) {
    float x = vals[v];
    for (int off = 1; off < 64; off <<= 1) x += __shfl_xor(x, off);
    vals[v] = x;
  }
  int lane = tid & 63, wv = tid >> 6;
  if (lane == 0) {
#pragma unroll
    for (int v = 0; v < 5; ++v) s_red[wv * 5 + v] = vals[v];
  }
  __syncthreads();
  if (tid == 0) {
#pragma unroll
    for (int v = 0; v < 5; ++v) {
      float s = s_red[v] + s_red[5 + v] + s_red[10 + v] + s_red[15 + v];
      atomicAdd(&accums[v], s);
    }
  }
}

// ---------------------------------------------------------------------------
// Kernel 5: finalize the two scalar outputs.
// ---------------------------------------------------------------------------
__global__ void k_fin(const float* __restrict__ accums,
                      const float* __restrict__ noise_std,
                      float* __restrict__ out) {
  if (threadIdx.x == 0 && blockIdx.x == 0) {
    float sd = noise_std[0];
    float log_pxs = -0.5f * accums[0] / (sd * sd * (float)B_SZ) -
                    (float)T_STEPS * 32.0f * (logf(sd) + 0.5f * LOG2PI);
    float land = accums[1] / (float)(T_STEPS * B_SZ * 2);
    float move = accums[2] / (float)(T_STEPS * B_SZ * 2);
    float shot = -accums[3] / fmaxf(accums[4], 1.0f);
    float out1 = accums[5] / (float)B_SZ + accums[6] / (float)B_SZ + land + shot + move;
    out[0] = log_pxs;
    out[1] = out1;
  }
}

// ---------------------------------------------------------------------------
extern "C" void kernel_launch(void* const* d_in, const int* in_sizes, int n_in,
                              void* d_out, int out_size, void* d_ws,
                              size_t ws_size, hipStream_t stream) {
  const float* xs = (const float*)d_in[1];
  const float* ts = (const float*)d_in[2];
  const float* noise_std = (const float*)d_in[3];
  const float* z0_noise = (const float*)d_in[4];
  const float* bm_noise = (const float*)d_in[5];
  const float* shot_emb = (const float*)d_in[6];
  const float* player_emb = (const float*)d_in[7];
  const float* gru_wih = (const float*)d_in[8];
  const float* gru_whh = (const float*)d_in[9];
  const float* gru_bih = (const float*)d_in[10];
  const float* gru_bhh = (const float*)d_in[11];
  const float* enc_w = (const float*)d_in[12];
  const float* enc_b = (const float*)d_in[13];
  const float* qz0_w = (const float*)d_in[14];
  const float* qz0_b = (const float*)d_in[15];
  const float* f_w1 = (const float*)d_in[16];
  const float* f_b1 = (const float*)d_in[17];
  const float* f_w2 = (const float*)d_in[18];
  const float* f_b2 = (const float*)d_in[19];
  const float* f_w3 = (const float*)d_in[20];
  const float* f_b3 = (const float*)d_in[21];
  const float* h_w1 = (const float*)d_in[22];
  const float* h_b1 = (const float*)d_in[23];
  const float* h_w2 = (const float*)d_in[24];
  const float* h_b2 = (const float*)d_in[25];
  const float* h_w3 = (const float*)d_in[26];
  const float* h_b3 = (const float*)d_in[27];
  const float* g_w1 = (const float*)d_in[28];
  const float* g_b1 = (const float*)d_in[29];
  const float* g_w2 = (const float*)d_in[30];
  const float* g_b2 = (const float*)d_in[31];
  const float* proj_w = (const float*)d_in[32];
  const float* proj_b = (const float*)d_in[33];
  const float* pz0_mean = (const float*)d_in[34];
  const float* pz0_logstd = (const float*)d_in[35];
  const float* act_w = (const float*)d_in[36];
  const float* act_b = (const float*)d_in[37];
  const float* act_land_w = (const float*)d_in[38];
  const float* act_shot_w = (const float*)d_in[39];
  const float* act_move_w = (const float*)d_in[40];

  char* ws = (char*)d_ws;
  float* accums = (float*)ws;                       // 16 floats (256 B reserved)
  f16* state_t = (f16*)(ws + 256);                  // T*B*32 f16 = 16 MB
  f16* ctx = (f16*)(ws + 256 + 16777216);           // T*B*64 f16 = 32 MB
  float* z0b = (float*)(ws + 256 + 16777216 + 33554432);   // B*16 f32
  f16* zs = (f16*)(ws + 256 + 16777216 + 33554432 + 32768);  // T*B*16 f16 = 8 MB

  k_embed<<<1024, 256, 0, stream>>>(xs, shot_emb, player_emb, state_t, accums);
  k_gru<<<256, 512, 0, stream>>>(state_t, gru_wih, gru_whh, gru_bih, gru_bhh,
                                 enc_w, enc_b, qz0_w, qz0_b, z0_noise, pz0_mean,
                                 pz0_logstd, ctx, z0b, accums);
  k_sde<<<512, 64, 0, stream>>>(ctx, z0b, ts, bm_noise, f_w1, f_b1, f_w2, f_b2,
                                f_w3, f_b3, h_w1, h_b1, h_w2, h_b2, h_w3, h_b3,
                                g_w1, g_b1, g_w2, g_b2, zs, accums);
  k_dec<<<1024, 256, 0, stream>>>(zs, state_t, xs, proj_w, proj_b, act_w, act_b,
                                  act_land_w, act_shot_w, act_move_w, accums);
  k_fin<<<1, 64, 0, stream>>>(accums, noise_std, (float*)d_out);
}

// Round 7
// 1685.854 us; speedup vs baseline: 1.9095x; 1.9095x over previous
//
#include <hip/hip_runtime.h>
#include <cstdint>

typedef _Float16 f16;
typedef _Float16 f16x2 __attribute__((ext_vector_type(2)));

#define T_STEPS 512
#define B_SZ 512
#define LOG2PI 1.8378770664093453f

// Raw barrier: drain LDS only (NOT vmcnt) so in-flight global prefetch loads
// and stores survive across the barrier.
__device__ __forceinline__ void barrier_lds() {
  asm volatile("s_waitcnt lgkmcnt(0)" ::: "memory");
  __builtin_amdgcn_s_barrier();
  asm volatile("" ::: "memory");
}

__device__ __forceinline__ uint32_t packh2(float a, float b) {
  f16x2 v; v[0] = (f16)a; v[1] = (f16)b;
  return __builtin_bit_cast(uint32_t, v);
}

__device__ __forceinline__ float fdot2(uint32_t a, uint32_t b, float c) {
#if defined(__AMDGCN__) && __has_builtin(__builtin_amdgcn_fdot2)
  return __builtin_amdgcn_fdot2(__builtin_bit_cast(f16x2, a),
                                __builtin_bit_cast(f16x2, b), c, false);
#else
  f16x2 x = __builtin_bit_cast(f16x2, a), y = __builtin_bit_cast(f16x2, b);
  return c + (float)x[0] * (float)y[0] + (float)x[1] * (float)y[1];
#endif
}

#define DOT4(acc, w0, w1, w2, w3, v)                                     \
  do {                                                                   \
    acc = fdot2((w0), (v).x, acc); acc = fdot2((w1), (v).y, acc);        \
    acc = fdot2((w2), (v).z, acc); acc = fdot2((w3), (v).w, acc);        \
  } while (0)

__device__ __forceinline__ float sigmoidf_(float x) {
  return 1.0f / (1.0f + __expf(-x));
}
__device__ __forceinline__ float tanhf_(float x) {
  float ax = fabsf(x);
  float t = __expf(-2.0f * ax);
  float r = (1.0f - t) / (1.0f + t);
  return copysignf(r, x);
}
__device__ __forceinline__ float softplusf_(float x) {
  return fmaxf(x, 0.0f) + __logf(1.0f + __expf(-fabsf(x)));
}

// ---------------------------------------------------------------------------
// Kernel 1: embedding / state_t construction.  state_t: (T,B,32) f16.
// ---------------------------------------------------------------------------
__global__ __launch_bounds__(256) void k_embed(
    const float* __restrict__ xs, const float* __restrict__ shot_emb,
    const float* __restrict__ player_emb, f16* __restrict__ state_t,
    float* __restrict__ accums) {
  if (blockIdx.x == 0 && threadIdx.x < 16) accums[threadIdx.x] = 0.0f;
  size_t idx = (size_t)blockIdx.x * 256 + threadIdx.x;
  const float* xp = xs + idx * 23;
  f16* op = state_t + idx * 32;
  int sid = (int)xp[12];
  int pid = (int)xp[17];
#pragma unroll
  for (int i = 0; i < 12; ++i) op[i] = (f16)xp[i];
  const float* se = shot_emb + sid * 8;
#pragma unroll
  for (int i = 0; i < 8; ++i) op[12 + i] = (f16)se[i];
#pragma unroll
  for (int i = 0; i < 4; ++i) op[20 + i] = (f16)xp[13 + i];
  const float* pe = player_emb + pid * 8;
#pragma unroll
  for (int i = 0; i < 8; ++i) op[24 + i] = (f16)pe[i];
}

// ---------------------------------------------------------------------------
// Kernel 1b: g-network lookup table.  g_l(y) is a scalar function of scalar y
// (per latent dim l): tabulate over ALL f16 bit patterns of y.
// g_tab[l*65536 + bits(f16 y)] = sigmoid(gb2[l] + sum_h softplus(y*w1+b1)*w2).
// 16 x 65536 f32 = 4 MB, L2/L3-resident during k_sde.
// ---------------------------------------------------------------------------
__global__ __launch_bounds__(256) void k_gtab(
    const float* __restrict__ gw1, const float* __restrict__ gb1,
    const float* __restrict__ gw2, const float* __restrict__ gb2,
    float* __restrict__ g_tab) {
  int gid = blockIdx.x * 256 + threadIdx.x;  // 4096 blocks -> 1,048,576 = 16*65536
  int l = gid >> 16, yi = gid & 0xffff;
  f16 hy = __builtin_bit_cast(f16, (unsigned short)yi);
  float y = (float)hy;
  const float* w1 = gw1 + l * 128;
  const float* b1 = gb1 + l * 128;
  const float* w2 = gw2 + l * 128;
  float a0 = 0.f, a1 = 0.f;
#pragma unroll 8
  for (int h = 0; h < 128; h += 2) {
    a0 = fmaf(softplusf_(fmaf(y, w1[h], b1[h])), w2[h], a0);
    a1 = fmaf(softplusf_(fmaf(y, w1[h + 1], b1[h + 1])), w2[h + 1], a1);
  }
  g_tab[gid] = sigmoidf_(a0 + a1 + gb2[l]);
}

// ---------------------------------------------------------------------------
// Kernel 2: backward GRU scan + encoder + qz0 head.  (R4-verified version)
// 256 blocks x 512 threads, 2 batch/block. Weights REGISTER-resident.
// ---------------------------------------------------------------------------
__global__ __launch_bounds__(512) void k_gru(
    const f16* __restrict__ state_t, const float* __restrict__ wih,
    const float* __restrict__ whh, const float* __restrict__ bih,
    const float* __restrict__ bhh, const float* __restrict__ enc_w,
    const float* __restrict__ enc_b, const float* __restrict__ qz0_w,
    const float* __restrict__ qz0_b, const float* __restrict__ z0_noise,
    const float* __restrict__ pz0_mean, const float* __restrict__ pz0_logstd,
    f16* __restrict__ ctx, float* __restrict__ z0_out,
    float* __restrict__ accums) {
  __shared__ uint32_t s_x[2][16];      // x_t, f16x2 packed
  __shared__ uint32_t s_h[2][64];      // h,   f16x2 packed
  __shared__ float s_gates[2 * 128 * 4];  // [b][du][R,Z,iN,hN]
  __shared__ float s_encp[2 * 64 * 2];    // [b][c][ks]
  __shared__ float s_ctx0[2][64];
  __shared__ float s_q[2][32];

  const int tid = threadIdx.x;
  const int bbase = blockIdx.x * 2;
  const uint32_t* stu = (const uint32_t*)state_t;

  uint32_t wA[64];   // whh row (RZ/N) | enc half-row (enc, 32 used)
  uint32_t wB[16];   // wih row (RZ/N)
  float bias0 = 0.f, bias1 = 0.f, encbr = 0.f;

  if (tid < 256) {
    int g = tid >> 7, du = tid & 127;
    const float* whr = whh + (size_t)(g * 128 + du) * 128;
#pragma unroll
    for (int i = 0; i < 64; ++i) wA[i] = packh2(whr[2 * i], whr[2 * i + 1]);
    const float* wxr = wih + (size_t)(g * 128 + du) * 32;
#pragma unroll
    for (int i = 0; i < 16; ++i) wB[i] = packh2(wxr[2 * i], wxr[2 * i + 1]);
    bias0 = bih[g * 128 + du] + bhh[g * 128 + du];
  } else if (tid < 384) {
    int du = tid - 256;
    const float* whr = whh + (size_t)(256 + du) * 128;
#pragma unroll
    for (int i = 0; i < 64; ++i) wA[i] = packh2(whr[2 * i], whr[2 * i + 1]);
    const float* wxr = wih + (size_t)(256 + du) * 32;
#pragma unroll
    for (int i = 0; i < 16; ++i) wB[i] = packh2(wxr[2 * i], wxr[2 * i + 1]);
    bias0 = bih[256 + du];
    bias1 = bhh[256 + du];
  } else {
    int e = tid - 384, c = e & 63, ks = e >> 6;
    const float* wer = enc_w + (size_t)c * 128 + ks * 64;
#pragma unroll
    for (int i = 0; i < 32; ++i) wA[i] = packh2(wer[2 * i], wer[2 * i + 1]);
    encbr = enc_b[c];
  }

  if (tid < 128) s_h[tid >> 6][tid & 63] = 0u;
  if (tid < 32) {
    int b = tid >> 4, i = tid & 15;
    s_x[b][i] = stu[((size_t)(T_STEPS - 1) * B_SZ + bbase + b) * 16 + i];
  }
  float h_old = 0.0f;
  __syncthreads();

  for (int t = T_STEPS - 1; t >= 0; --t) {
    uint4 xpref = make_uint4(0, 0, 0, 0);
    // ---- Phase A: gate dots (R/Z/N) + enc dots for h(t+1) + x prefetch
    if (tid < 256) {
      int g = tid >> 7, du = tid & 127;
#pragma unroll
      for (int b = 0; b < 2; ++b) {
        float a = bias0;
        const uint4* xq = (const uint4*)&s_x[b][0];
#pragma unroll
        for (int j = 0; j < 4; ++j) {
          uint4 v = xq[j];
          DOT4(a, wB[4 * j], wB[4 * j + 1], wB[4 * j + 2], wB[4 * j + 3], v);
        }
        const uint4* hq = (const uint4*)&s_h[b][0];
#pragma unroll
        for (int j = 0; j < 16; ++j) {
          uint4 v = hq[j];
          DOT4(a, wA[4 * j], wA[4 * j + 1], wA[4 * j + 2], wA[4 * j + 3], v);
        }
        s_gates[(b * 128 + du) * 4 + g] = a;
      }
    } else if (tid < 384) {
      int du = tid - 256;
#pragma unroll
      for (int b = 0; b < 2; ++b) {
        float aI = bias0, aH = bias1;
        const uint4* xq = (const uint4*)&s_x[b][0];
#pragma unroll
        for (int j = 0; j < 4; ++j) {
          uint4 v = xq[j];
          DOT4(aI, wB[4 * j], wB[4 * j + 1], wB[4 * j + 2], wB[4 * j + 3], v);
        }
        const uint4* hq = (const uint4*)&s_h[b][0];
#pragma unroll
        for (int j = 0; j < 16; ++j) {
          uint4 v = hq[j];
          DOT4(aH, wA[4 * j], wA[4 * j + 1], wA[4 * j + 2], wA[4 * j + 3], v);
        }
        s_gates[(b * 128 + du) * 4 + 2] = aI;
        s_gates[(b * 128 + du) * 4 + 3] = aH;
      }
    } else {
      int e = tid - 384, ks = e >> 6, cc = e & 63;
      (void)cc;
      if (t < T_STEPS - 1) {
#pragma unroll
        for (int b = 0; b < 2; ++b) {
          float a = 0.f;
          const uint4* hq = (const uint4*)&s_h[b][ks * 32];
#pragma unroll
          for (int j = 0; j < 8; ++j) {
            uint4 v = hq[j];
            DOT4(a, wA[4 * j], wA[4 * j + 1], wA[4 * j + 2], wA[4 * j + 3], v);
          }
          s_encp[(b * 64 + cc) * 2 + ks] = a;
        }
      }
      if (e < 8 && t > 0) {
        int b = e & 1, q = e >> 1;
        xpref = *(const uint4*)(stu +
                                ((size_t)(t - 1) * B_SZ + bbase + b) * 16 + q * 4);
      }
    }
    barrier_lds();
    // ---- Phase B: h update; ctx combine; x stage
    if (tid < 256) {
      int b = tid >> 7, du = tid & 127;
      const float4 gt = *(const float4*)&s_gates[(b * 128 + du) * 4];
      float r = sigmoidf_(gt.x), zg = sigmoidf_(gt.y);
      float n = tanhf_(gt.z + r * gt.w);
      float hnew = (1.0f - zg) * n + zg * h_old;
      h_old = hnew;
      ((f16*)&s_h[b][0])[du] = (f16)hnew;
    } else if (tid >= 384) {
      int e = tid - 384, cc = e & 63, b = e >> 6;
      if (t < T_STEPS - 1) {
        float2 p = *(const float2*)&s_encp[(b * 64 + cc) * 2];
        ctx[((size_t)(t + 1) * B_SZ + bbase + b) * 64 + cc] =
            (f16)(p.x + p.y + encbr);
      }
      if (e < 8 && t > 0) {
        int b2 = e & 1, q = e >> 1;
        *(uint4*)&s_x[b2][q * 4] = xpref;
      }
    }
    barrier_lds();
  }

  // ---- Tail: enc(h(0)) -> ctx[0] + s_ctx0; qz0 head; z0 + KL
  if (tid >= 384) {
    int e = tid - 384, ks = e >> 6, cc = e & 63;
#pragma unroll
    for (int b = 0; b < 2; ++b) {
      float a = 0.f;
      const uint4* hq = (const uint4*)&s_h[b][ks * 32];
#pragma unroll
      for (int j = 0; j < 8; ++j) {
        uint4 v = hq[j];
        DOT4(a, wA[4 * j], wA[4 * j + 1], wA[4 * j + 2], wA[4 * j + 3], v);
      }
      s_encp[(b * 64 + cc) * 2 + ks] = a;
    }
  }
  __syncthreads();
  if (tid >= 384) {
    int e = tid - 384, cc = e & 63, b = e >> 6;
    float2 p = *(const float2*)&s_encp[(b * 64 + cc) * 2];
    float val = p.x + p.y + encbr;
    ctx[((size_t)bbase + b) * 64 + cc] = (f16)val;
    s_ctx0[b][cc] = val;
  }
  __syncthreads();
  if (tid < 64) {
    int b = tid >> 5, o = tid & 31;
    float acc = qz0_b[o];
#pragma unroll 8
    for (int k = 0; k < 64; ++k) acc += qz0_w[o * 64 + k] * s_ctx0[b][k];
    s_q[b][o] = acc;
  }
  __syncthreads();
  if (tid < 32) {
    int b = tid >> 4, l = tid & 15;
    int bg = bbase + b;
    float qm = s_q[b][l], qls = s_q[b][16 + l];
    float z0v = qm + __expf(qls) * z0_noise[bg * 16 + l];
    z0_out[bg * 16 + l] = z0v;
    float pm = pz0_mean[l], pls = pz0_logstd[l];
    float var_q = __expf(2.0f * qls);
    float var_p = __expf(2.0f * pls);
    float dm = qm - pm;
    float kl = pls - qls + (var_q + dm * dm) / (2.0f * var_p) - 0.5f;
    atomicAdd(&accums[5], kl);
  }
}

// ---------------------------------------------------------------------------
// Kernel 3: SDE Euler-Maruyama scan (511 steps).  512 blocks x 256 threads,
// ONE batch/block, 2 blocks/CU, 3 LDS-only barriers/step.
// g-network replaced by table lookup: z-lanes issue the g_tab load in P1
// (index = f16 bits of z, same f16 the f/h nets consume) and use it in P3 —
// latency hidden across two barriers.  All g compute/LDS deleted.
// ---------------------------------------------------------------------------
__global__ __launch_bounds__(256, 2) void k_sde(
    const f16* __restrict__ ctx, const float* __restrict__ z0_in,
    const float* __restrict__ ts, const float* __restrict__ bm_noise,
    const float* __restrict__ fw1, const float* __restrict__ fb1,
    const float* __restrict__ fw2, const float* __restrict__ fb2,
    const float* __restrict__ fw3, const float* __restrict__ fb3,
    const float* __restrict__ hw1, const float* __restrict__ hb1,
    const float* __restrict__ hw2, const float* __restrict__ hb2,
    const float* __restrict__ hw3, const float* __restrict__ hb3,
    const float* __restrict__ g_tab,
    f16* __restrict__ zs, float* __restrict__ accums) {
  __shared__ uint32_t s_x2[40];       // [z(8 u32) | ctx(32 u32)] f16x2
  __shared__ uint32_t s_h1[2][64];    // [mlp] layer-1 act, f16x2
  __shared__ uint32_t s_h2[2][64];    // [mlp] layer-2 act, f16x2
  __shared__ float s_dts[T_STEPS];

  const int tid = threadIdx.x;
  const int bg = blockIdx.x;  // batch element
  const uint32_t* cu = (const uint32_t*)ctx;
  const int l = tid >> 2;
  const bool zlane = (tid < 64) && ((tid & 3) == 0);

  // ---- weight preload into registers
  uint32_t uw1[40];                     // f1 row (tid<128) | h1 row (8 used)
  uint32_t wP2[64];                     // layer-2 full row
  uint32_t wP3[32];                     // layer-3 half row (tid<64)
  float bias1r = 0.f, bias2r = 0.f, fb3r = 0.f, hb3r = 0.f;

  if (tid < 128) {
    const float* w = fw1 + (size_t)tid * 80;
#pragma unroll
    for (int i = 0; i < 40; ++i) uw1[i] = packh2(w[2 * i], w[2 * i + 1]);
    bias1r = fb1[tid];
  } else {
    int u = tid - 128;
    const float* w = hw1 + (size_t)u * 16;
#pragma unroll
    for (int i = 0; i < 8; ++i) uw1[i] = packh2(w[2 * i], w[2 * i + 1]);
    bias1r = hb1[u];
  }
  {
    int mlp = tid >> 7, u = tid & 127;
    const float* w = (mlp ? hw2 : fw2) + (size_t)u * 128;
#pragma unroll
    for (int i = 0; i < 64; ++i) wP2[i] = packh2(w[2 * i], w[2 * i + 1]);
    bias2r = (mlp ? hb2 : fb2)[u];
  }
  if (tid < 64) {
    int mlp = (tid >> 1) & 1, kh = tid & 1;
    const float* w = (mlp ? hw3 : fw3) + (size_t)l * 128 + kh * 64;
#pragma unroll
    for (int i = 0; i < 32; ++i) wP3[i] = packh2(w[2 * i], w[2 * i + 1]);
    if ((tid & 3) == 0) {
      fb3r = fb3[l];
      hb3r = hb3[l];
    }
  }

  // ---- state init
  for (int i = tid; i < T_STEPS - 1; i += 256) s_dts[i] = ts[i + 1] - ts[i];
  float zreg = 0.f, bmc = 0.f, path_acc = 0.f;
  uint4 cpref = make_uint4(0, 0, 0, 0);
  if (zlane) {
    zreg = z0_in[bg * 16 + l];
    ((f16*)&s_x2[0])[l] = (f16)zreg;
    zs[(size_t)bg * 16 + l] = (f16)zreg;
    bmc = bm_noise[(size_t)bg * 16 + l];
  }
  if (tid >= 128 && tid < 136) {
    int q = tid - 128;
    uint4 v = *(const uint4*)(cu + ((size_t)1 * B_SZ + bg) * 32 + q * 4);
    *(uint4*)&s_x2[8 + q * 4] = v;
  }
  __syncthreads();

  for (int t = 0; t < T_STEPS - 1; ++t) {
    float bmn = 0.f, gvp = 0.f;
    // ---- issue g-table load (consumed in P3) + prefetch bm(t+1), ctx(t+2)
    if (zlane) {
      unsigned short zb = __builtin_bit_cast(unsigned short, (f16)zreg);
      gvp = g_tab[l * 65536 + (int)zb];
      if (t < T_STEPS - 2)
        bmn = bm_noise[((size_t)(t + 1) * B_SZ + bg) * 16 + l];
    }
    if (tid >= 128 && tid < 136 && t <= T_STEPS - 3) {
      int q = tid - 128;
      cpref = *(const uint4*)(cu + ((size_t)(t + 2) * B_SZ + bg) * 32 + q * 4);
    }
    // ---- P1: f1 rows (tid<128) / h1 rows (tid>=128)
    if (tid < 128) {
      float a0 = bias1r, a1 = 0.f;
      const uint4* xq = (const uint4*)&s_x2[0];
#pragma unroll
      for (int j = 0; j < 10; j += 2) {
        uint4 v0 = xq[j], v1 = xq[j + 1];
        DOT4(a0, uw1[4 * j], uw1[4 * j + 1], uw1[4 * j + 2], uw1[4 * j + 3], v0);
        DOT4(a1, uw1[4 * j + 4], uw1[4 * j + 5], uw1[4 * j + 6], uw1[4 * j + 7], v1);
      }
      ((f16*)&s_h1[0][0])[tid] = (f16)softplusf_(a0 + a1);
    } else {
      float a = bias1r;
      const uint4* xq = (const uint4*)&s_x2[0];
#pragma unroll
      for (int j = 0; j < 2; ++j) {
        uint4 v = xq[j];
        DOT4(a, uw1[4 * j], uw1[4 * j + 1], uw1[4 * j + 2], uw1[4 * j + 3], v);
      }
      ((f16*)&s_h1[1][0])[tid - 128] = (f16)softplusf_(a);
    }
    barrier_lds();
    // ---- P2: full layer-2 rows (all 256)
    {
      int mlp = tid >> 7, u = tid & 127;
      float a0 = 0.f, a1 = 0.f;
      const uint4* hq = (const uint4*)&s_h1[mlp][0];
#pragma unroll
      for (int j = 0; j < 16; j += 2) {
        uint4 v0 = hq[j], v1 = hq[j + 1];
        DOT4(a0, wP2[4 * j], wP2[4 * j + 1], wP2[4 * j + 2], wP2[4 * j + 3], v0);
        DOT4(a1, wP2[4 * j + 4], wP2[4 * j + 5], wP2[4 * j + 6], wP2[4 * j + 7], v1);
      }
      ((f16*)&s_h2[mlp][0])[u] = (f16)softplusf_(a0 + a1 + bias2r);
    }
    barrier_lds();
    // ---- P3: layer-3 half-rows + z update (shfl combines); ctx stage
    if (tid < 64) {
      int kh = tid & 1;
      int mlp = (tid >> 1) & 1;
      const uint4* hq = (const uint4*)&s_h2[mlp][kh * 32];
      float a0 = 0.f, a1 = 0.f;
#pragma unroll
      for (int j = 0; j < 8; j += 2) {
        uint4 v0 = hq[j], v1 = hq[j + 1];
        DOT4(a0, wP3[4 * j], wP3[4 * j + 1], wP3[4 * j + 2], wP3[4 * j + 3], v0);
        DOT4(a1, wP3[4 * j + 4], wP3[4 * j + 5], wP3[4 * j + 6], wP3[4 * j + 7], v1);
      }
      float a = a0 + a1;
      float full = a + __shfl_xor(a, 1);   // combine kh halves
      float other = __shfl_xor(full, 2);   // exchange f <-> h
      if ((tid & 3) == 0) {
        float fv = full + fb3r;
        float hv = other + hb3r;
        float gv = gvp;                    // table value, loaded in P1
        float dt = s_dts[t];
        float u_ = (fv - hv) / gv;
        float lsum = u_ * u_;
        lsum += __shfl_xor(lsum, 4);
        lsum += __shfl_xor(lsum, 8);
        lsum += __shfl_xor(lsum, 16);
        lsum += __shfl_xor(lsum, 32);
        if (tid == 0) path_acc += 0.5f * lsum * dt;
        float dw = sqrtf(dt) * bmc;
        float zn = zreg + fv * dt + gv * dw;
        zreg = zn;
        ((f16*)&s_x2[0])[l] = (f16)zn;
        zs[((size_t)(t + 1) * B_SZ + bg) * 16 + l] = (f16)zn;
        bmc = bmn;
      }
    } else if (tid >= 128 && tid < 136 && t <= T_STEPS - 3) {
      int q = tid - 128;
      *(uint4*)&s_x2[8 + q * 4] = cpref;
    }
    barrier_lds();
  }
  if (tid == 0) atomicAdd(&accums[6], path_acc);
}

// ---------------------------------------------------------------------------
// Kernel 4: decoder + losses.  One thread per (t,b).
// ---------------------------------------------------------------------------
__global__ __launch_bounds__(256) void k_dec(
    const f16* __restrict__ zs, const f16* __restrict__ state_t,
    const float* __restrict__ xs, const float* __restrict__ proj_w,
    const float* __restrict__ proj_b, const float* __restrict__ act_w,
    const float* __restrict__ act_b, const float* __restrict__ land_w,
    const float* __restrict__ shot_w, const float* __restrict__ move_w,
    float* __restrict__ accums) {
  __shared__ uint32_t s_proj[8 * 32];
  __shared__ uint32_t s_act[8 * 128];
  __shared__ uint32_t s_head[128 * 8];
  __shared__ float s_pb[32], s_ab[128];
  __shared__ float s_red[4 * 5];

  const int tid = threadIdx.x;
  for (int id = tid; id < 8 * 32; id += 256) {
    int kp = id & 7, n = id >> 3;
    s_proj[kp * 32 + n] = packh2(proj_w[n * 16 + 2 * kp], proj_w[n * 16 + 2 * kp + 1]);
  }
  for (int id = tid; id < 8 * 128; id += 256) {
    int kp = id & 7, n = id >> 3;
    s_act[kp * 128 + n] = packh2(act_w[n * 16 + 2 * kp], act_w[n * 16 + 2 * kp + 1]);
  }
  for (int id = tid; id < 128 * 8; id += 256) {
    int j = id >> 3, p = id & 7;
    int h0 = 2 * p, h1 = 2 * p + 1;
    float w0 = (h0 < 2) ? land_w[h0 * 128 + j]
                        : (h0 < 14 ? shot_w[(h0 - 2) * 128 + j]
                                   : move_w[(h0 - 14) * 128 + j]);
    float w1 = (h1 < 2) ? land_w[h1 * 128 + j]
                        : (h1 < 14 ? shot_w[(h1 - 2) * 128 + j]
                                   : move_w[(h1 - 14) * 128 + j]);
    s_head[j * 8 + p] = packh2(w0, w1);
  }
  if (tid < 32) s_pb[tid] = proj_b[tid];
  if (tid < 128) s_ab[tid] = act_b[tid];
  __syncthreads();

  size_t idx = (size_t)blockIdx.x * 256 + tid;
  uint32_t z2[8];
  const uint32_t* zp = (const uint32_t*)(zs + idx * 16);
#pragma unroll
  for (int i = 0; i < 8; ++i) z2[i] = zp[i];
  uint32_t stv[16];
  const uint32_t* stp = (const uint32_t*)(state_t + idx * 32);
#pragma unroll
  for (int i = 0; i < 16; ++i) stv[i] = stp[i];

  float sqsum = 0.0f;
#pragma unroll 4
  for (int i = 0; i < 32; ++i) {
    float acc = s_pb[i];
#pragma unroll
    for (int kp = 0; kp < 8; ++kp) acc = fdot2(s_proj[kp * 32 + i], z2[kp], acc);
    f16x2 sv = __builtin_bit_cast(f16x2, stv[i >> 1]);
    float d = (float)sv[i & 1] - acc;
    sqsum += d * d;
  }

  float hd[16];
#pragma unroll
  for (int i = 0; i < 16; ++i) hd[i] = 0.0f;
#pragma unroll 2
  for (int j = 0; j < 128; ++j) {
    float a = s_ab[j];
#pragma unroll
    for (int kp = 0; kp < 8; ++kp) a = fdot2(s_act[kp * 128 + j], z2[kp], a);
    a = fmaxf(a, 0.0f);
#pragma unroll
    for (int p = 0; p < 8; ++p) {
      f16x2 w = __builtin_bit_cast(f16x2, s_head[j * 8 + p]);
      hd[2 * p] += (float)w[0] * a;
      hd[2 * p + 1] += (float)w[1] * a;
    }
  }
  const float* xp = xs + idx * 23;
  float dl0 = hd[0] - xp[18], dl1 = hd[1] - xp[19];
  float land = dl0 * dl0 + dl1 * dl1;
  float dm0 = hd[14] - xp[21], dm1 = hd[15] - xp[22];
  float move = dm0 * dm0 + dm1 * dm1;
  int sid = (int)xp[20];
  float m = hd[2];
#pragma unroll
  for (int s = 1; s < 12; ++s) m = fmaxf(m, hd[2 + s]);
  float sume = 0.0f;
#pragma unroll
  for (int s = 0; s < 12; ++s) sume += __expf(hd[2 + s] - m);
  float lse = m + __logf(sume);
  float pl = 0.0f;
#pragma unroll
  for (int s = 0; s < 12; ++s)
    if (s == sid) pl = hd[2 + s];
  float picked = 0.0f, cnt = 0.0f;
  if (sid != 0) {
    picked = pl - lse;
    cnt = 1.0f;
  }
  float vals[5] = {sqsum, land, move, picked, cnt};
#pragma unroll
  for (int v = 0; v < 5; ++v) {
    float x = vals[v];
    for (int off = 1; off < 64; off <<= 1) x += __shfl_xor(x, off);
    vals[v] = x;
  }
  int lane = tid & 63, wv = tid >> 6;
  if (lane == 0) {
#pragma unroll
    for (int v = 0; v < 5; ++v) s_red[wv * 5 + v] = vals[v];
  }
  __syncthreads();
  if (tid == 0) {
#pragma unroll
    for (int v = 0; v < 5; ++v) {
      float s = s_red[v] + s_red[5 + v] + s_red[10 + v] + s_red[15 + v];
      atomicAdd(&accums[v], s);
    }
  }
}

// ---------------------------------------------------------------------------
// Kernel 5: finalize the two scalar outputs.
// ---------------------------------------------------------------------------
__global__ void k_fin(const float* __restrict__ accums,
                      const float* __restrict__ noise_std,
                      float* __restrict__ out) {
  if (threadIdx.x == 0 && blockIdx.x == 0) {
    float sd = noise_std[0];
    float log_pxs = -0.5f * accums[0] / (sd * sd * (float)B_SZ) -
                    (float)T_STEPS * 32.0f * (logf(sd) + 0.5f * LOG2PI);
    float land = accums[1] / (float)(T_STEPS * B_SZ * 2);
    float move = accums[2] / (float)(T_STEPS * B_SZ * 2);
    float shot = -accums[3] / fmaxf(accums[4], 1.0f);
    float out1 = accums[5] / (float)B_SZ + accums[6] / (float)B_SZ + land + shot + move;
    out[0] = log_pxs;
    out[1] = out1;
  }
}

// ---------------------------------------------------------------------------
extern "C" void kernel_launch(void* const* d_in, const int* in_sizes, int n_in,
                              void* d_out, int out_size, void* d_ws,
                              size_t ws_size, hipStream_t stream) {
  const float* xs = (const float*)d_in[1];
  const float* ts = (const float*)d_in[2];
  const float* noise_std = (const float*)d_in[3];
  const float* z0_noise = (const float*)d_in[4];
  const float* bm_noise = (const float*)d_in[5];
  const float* shot_emb = (const float*)d_in[6];
  const float* player_emb = (const float*)d_in[7];
  const float* gru_wih = (const float*)d_in[8];
  const float* gru_whh = (const float*)d_in[9];
  const float* gru_bih = (const float*)d_in[10];
  const float* gru_bhh = (const float*)d_in[11];
  const float* enc_w = (const float*)d_in[12];
  const float* enc_b = (const float*)d_in[13];
  const float* qz0_w = (const float*)d_in[14];
  const float* qz0_b = (const float*)d_in[15];
  const float* f_w1 = (const float*)d_in[16];
  const float* f_b1 = (const float*)d_in[17];
  const float* f_w2 = (const float*)d_in[18];
  const float* f_b2 = (const float*)d_in[19];
  const float* f_w3 = (const float*)d_in[20];
  const float* f_b3 = (const float*)d_in[21];
  const float* h_w1 = (const float*)d_in[22];
  const float* h_b1 = (const float*)d_in[23];
  const float* h_w2 = (const float*)d_in[24];
  const float* h_b2 = (const float*)d_in[25];
  const float* h_w3 = (const float*)d_in[26];
  const float* h_b3 = (const float*)d_in[27];
  const float* g_w1 = (const float*)d_in[28];
  const float* g_b1 = (const float*)d_in[29];
  const float* g_w2 = (const float*)d_in[30];
  const float* g_b2 = (const float*)d_in[31];
  const float* proj_w = (const float*)d_in[32];
  const float* proj_b = (const float*)d_in[33];
  const float* pz0_mean = (const float*)d_in[34];
  const float* pz0_logstd = (const float*)d_in[35];
  const float* act_w = (const float*)d_in[36];
  const float* act_b = (const float*)d_in[37];
  const float* act_land_w = (const float*)d_in[38];
  const float* act_shot_w = (const float*)d_in[39];
  const float* act_move_w = (const float*)d_in[40];

  char* ws = (char*)d_ws;
  float* accums = (float*)ws;                       // 16 floats (256 B reserved)
  f16* state_t = (f16*)(ws + 256);                  // T*B*32 f16 = 16 MB
  f16* ctx = (f16*)(ws + 256 + 16777216);           // T*B*64 f16 = 32 MB
  float* z0b = (float*)(ws + 256 + 16777216 + 33554432);   // B*16 f32
  f16* zs = (f16*)(ws + 256 + 16777216 + 33554432 + 32768);  // T*B*16 f16 = 8 MB
  float* g_tab = (float*)(ws + 256 + 16777216 + 33554432 + 32768 + 8388608);  // 16*65536 f32 = 4 MB

  k_embed<<<1024, 256, 0, stream>>>(xs, shot_emb, player_emb, state_t, accums);
  k_gtab<<<4096, 256, 0, stream>>>(g_w1, g_b1, g_w2, g_b2, g_tab);
  k_gru<<<256, 512, 0, stream>>>(state_t, gru_wih, gru_whh, gru_bih, gru_bhh,
                                 enc_w, enc_b, qz0_w, qz0_b, z0_noise, pz0_mean,
                                 pz0_logstd, ctx, z0b, accums);
  k_sde<<<512, 256, 0, stream>>>(ctx, z0b, ts, bm_noise, f_w1, f_b1, f_w2, f_b2,
                                 f_w3, f_b3, h_w1, h_b1, h_w2, h_b2, h_w3, h_b3,
                                 g_tab, zs, accums);
  k_dec<<<1024, 256, 0, stream>>>(zs, state_t, xs, proj_w, proj_b, act_w, act_b,
                                  act_land_w, act_shot_w, act_move_w, accums);
  k_fin<<<1, 64, 0, stream>>>(accums, noise_std, (float*)d_out);
}